// Round 4
// baseline (747.508 us; speedup 1.0000x reference)
//
#include <hip/hip_runtime.h>
#include <math.h>

#define N_NODES 100000
#define N_EDGES 1600000
#define DIM 128

typedef short bf16x8 __attribute__((ext_vector_type(8)));
typedef float f32x4 __attribute__((ext_vector_type(4)));

// ---- bf16 helpers (RNE pack, cheap unpack) ----
static __device__ __forceinline__ unsigned bf16rne(float f) {
    unsigned u = __float_as_uint(f);
    return (u + 0x7FFFu + ((u >> 16) & 1u)) >> 16;
}
static __device__ __forceinline__ float bflo(unsigned u) { return __uint_as_float(u << 16); }
static __device__ __forceinline__ float bfhi(unsigned u) { return __uint_as_float(u & 0xFFFF0000u); }

// ================= prep: zero deg/cur, split Wq/Wl to global, cast x->bf16,
// ================= k_act = bf16(lrelu(x @ (Wkhi+Wklo))) via MFMA =================
// grid 782 x 256; each block handles 128 node rows.

__global__ __launch_bounds__(256) void prep_k(
    const float* __restrict__ x, const float* __restrict__ Wq,
    const float* __restrict__ Wk, const float* __restrict__ Wl,
    ushort* __restrict__ xb, ushort* __restrict__ kactb,
    ushort* __restrict__ WqTh, ushort* __restrict__ WqTl,
    ushort* __restrict__ WlTh, ushort* __restrict__ WlTl,
    int* __restrict__ zero_base) {
    __shared__ ushort bh[128 * 136];
    __shared__ ushort blo[128 * 136];
    int t = threadIdx.x;

    // zero deg+cur (2*N ints; grid*256 = 200192 covers it)
    int zi = blockIdx.x * 256 + t;
    if (zi < 2 * N_NODES) zero_base[zi] = 0;

    // blocks 0,1: split Wq / Wl into transposed [n][k] bf16 hi/lo (global)
    if (blockIdx.x < 2) {
        const float* W = (blockIdx.x == 0) ? Wq : Wl;
        ushort* Th = (blockIdx.x == 0) ? WqTh : WlTh;
        ushort* Tl = (blockIdx.x == 0) ? WqTl : WlTl;
        for (int i = t; i < 16384; i += 256) {
            int k = i >> 7, n = i & 127;
            float v = W[i];
            unsigned hi = bf16rne(v);
            float lo = v - bflo(hi);
            Th[n * 128 + k] = (ushort)hi;
            Tl[n * 128 + k] = (ushort)bf16rne(lo);
        }
    }
    // stage WkT hi/lo in LDS (transposed, padded stride 136 shorts)
    for (int i = t; i < 16384; i += 256) {
        int k = i >> 7, n = i & 127;
        float v = Wk[i];
        unsigned hi = bf16rne(v);
        float lo = v - bflo(hi);
        bh[n * 136 + k] = (ushort)hi;
        blo[n * 136 + k] = (ushort)bf16rne(lo);
    }
    __syncthreads();

    int wave = t >> 6, lane = t & 63;
    int ln15 = lane & 15, quad = lane >> 4;
    long base = (long)blockIdx.x * 128 + wave * 32;

    bf16x8 Af[2][4];
#pragma unroll
    for (int r = 0; r < 2; r++) {
        long row = base + r * 16 + ln15;
        long rowc = row < N_NODES ? row : N_NODES - 1;
#pragma unroll
        for (int s = 0; s < 4; s++) {
            int ch = s * 4 + quad;  // 8-feat chunk index
            const float4* xp = (const float4*)(x + rowc * 128 + ch * 8);
            float4 u0 = xp[0], u1 = xp[1];
            bf16x8 f;
            f[0] = (short)bf16rne(u0.x); f[1] = (short)bf16rne(u0.y);
            f[2] = (short)bf16rne(u0.z); f[3] = (short)bf16rne(u0.w);
            f[4] = (short)bf16rne(u1.x); f[5] = (short)bf16rne(u1.y);
            f[6] = (short)bf16rne(u1.z); f[7] = (short)bf16rne(u1.w);
            Af[r][s] = f;
            if (row < N_NODES) *(bf16x8*)(xb + row * 128 + ch * 8) = f;
        }
    }
    f32x4 acc[2][8];
#pragma unroll
    for (int r = 0; r < 2; r++)
#pragma unroll
        for (int t8 = 0; t8 < 8; t8++) acc[r][t8] = (f32x4){0.f, 0.f, 0.f, 0.f};
#pragma unroll
    for (int phase = 0; phase < 2; phase++) {
        const ushort* B = phase ? blo : bh;
#pragma unroll
        for (int s = 0; s < 4; s++) {
#pragma unroll
            for (int t8 = 0; t8 < 8; t8++) {
                bf16x8 b = *(const bf16x8*)(B + (t8 * 16 + ln15) * 136 + (s * 4 + quad) * 8);
                acc[0][t8] = __builtin_amdgcn_mfma_f32_16x16x32_bf16(Af[0][s], b, acc[0][t8], 0, 0, 0);
                acc[1][t8] = __builtin_amdgcn_mfma_f32_16x16x32_bf16(Af[1][s], b, acc[1][t8], 0, 0, 0);
            }
        }
    }
#pragma unroll
    for (int r = 0; r < 2; r++) {
#pragma unroll
        for (int reg = 0; reg < 4; reg++) {
            long node = base + r * 16 + quad * 4 + reg;
            if (node < N_NODES) {
#pragma unroll
                for (int t8 = 0; t8 < 8; t8++) {
                    float v = acc[r][t8][reg];
                    v = v > 0.f ? v : 0.2f * v;
                    kactb[node * 128 + t8 * 16 + ln15] = (ushort)bf16rne(v);
                }
            }
        }
    }
}

// ================= CSR build =================

__global__ void hist_k(const int* __restrict__ row, int* __restrict__ deg) {
    int e = blockIdx.x * 256 + threadIdx.x;
    if (e < N_EDGES) atomicAdd(&deg[row[e]], 1);
}

// single-block exclusive scan of deg[0..N) -> offs  (two-level shuffle scan)
__global__ __launch_bounds__(1024) void scan_k(const int* __restrict__ deg,
                                               int* __restrict__ offs) {
    __shared__ int wsum[16];
    __shared__ int carry_s;
    int t = threadIdx.x, wid = t >> 6, lane = t & 63;
    if (t == 0) carry_s = 0;
    __syncthreads();
    const int4* d4 = (const int4*)deg;   // N/4 = 25000
    int4* o4 = (int4*)offs;
    for (int base4 = 0; base4 < 25000; base4 += 2048) {
        int i0 = base4 + t * 2, i1 = i0 + 1;
        int4 z4 = {0, 0, 0, 0};
        int4 va = (i0 < 25000) ? d4[i0] : z4;
        int4 vb = (i1 < 25000) ? d4[i1] : z4;
        int e1 = va.x, e2 = e1 + va.y, e3 = e2 + va.z, e4 = e3 + va.w;
        int e5 = e4 + vb.x, e6 = e5 + vb.y, e7 = e6 + vb.z, s = e7 + vb.w;
        int incl = s;
#pragma unroll
        for (int off = 1; off < 64; off <<= 1) {
            int y = __shfl_up(incl, off, 64);
            if (lane >= off) incl += y;
        }
        if (lane == 63) wsum[wid] = incl;
        __syncthreads();
        if (t < 16) {
            int w = wsum[t];
            int wi = w;
#pragma unroll
            for (int off = 1; off < 16; off <<= 1) {
                int y = __shfl_up(wi, off, 64);
                if (t >= off) wi += y;
            }
            wsum[t] = wi - w;  // exclusive wave prefix
        }
        __syncthreads();
        int excl = carry_s + wsum[wid] + incl - s;
        int4 oa = {excl, excl + e1, excl + e2, excl + e3};
        int4 ob = {excl + e4, excl + e5, excl + e6, excl + e7};
        if (i0 < 25000) o4[i0] = oa;
        if (i1 < 25000) o4[i1] = ob;
        __syncthreads();
        if (t == 1023) carry_s = excl + s;
        __syncthreads();
    }
}

__global__ void scatter_k(const int* __restrict__ row, const int* __restrict__ col,
                          const int* __restrict__ offs, int* __restrict__ cur,
                          int* __restrict__ scol) {
    int e = blockIdx.x * 256 + threadIdx.x;
    if (e < N_EDGES) {
        int r = row[e];
        int p = offs[r] + atomicAdd(&cur[r], 1);
        scol[p] = col[e];
    }
}

// ================= xagg gather + Wq GEMM fused =================
// grid 782 x 256: 16 groups of 16 lanes gather 8 nodes each into LDS (bf16),
// then 4 waves run the 128x128 hi/lo MFMA GEMM -> qaggb. No xagg global array.

__global__ __launch_bounds__(256) void xaggq_k(
    const ushort* __restrict__ xb, const int* __restrict__ offs,
    const int* __restrict__ deg, const int* __restrict__ scol,
    const ushort* __restrict__ WqTh, const ushort* __restrict__ WqTl,
    ushort* __restrict__ qaggb) {
    __shared__ ushort xs[128 * 136];  // 34.8 KB, stride-136 pad (2-way = free)
    int t = threadIdx.x;
    int grp = t >> 4, gl = t & 15;
    long nb = (long)blockIdx.x * 128;

    for (int i = 0; i < 8; i++) {
        int r = grp * 8 + i;
        long g = nb + r;
        int s = 0, d = 0;
        if (g < N_NODES) { s = offs[g]; d = deg[g]; }
        float a0 = 0.f, a1 = 0.f, a2 = 0.f, a3 = 0.f;
        float a4 = 0.f, a5 = 0.f, a6 = 0.f, a7 = 0.f;
        for (int e = 0; e < d; e++) {
            int c = scol[s + e];
            uint4 u = *(const uint4*)(xb + (size_t)c * 128 + gl * 8);
            a0 += bflo(u.x); a1 += bfhi(u.x);
            a2 += bflo(u.y); a3 += bfhi(u.y);
            a4 += bflo(u.z); a5 += bfhi(u.z);
            a6 += bflo(u.w); a7 += bfhi(u.w);
        }
        bf16x8 o;
        o[0] = (short)bf16rne(a0); o[1] = (short)bf16rne(a1);
        o[2] = (short)bf16rne(a2); o[3] = (short)bf16rne(a3);
        o[4] = (short)bf16rne(a4); o[5] = (short)bf16rne(a5);
        o[6] = (short)bf16rne(a6); o[7] = (short)bf16rne(a7);
        *(bf16x8*)(xs + r * 136 + gl * 8) = o;
    }
    __syncthreads();

    int wave = t >> 6, lane = t & 63;
    int ln15 = lane & 15, quad = lane >> 4;
    int rowbase = wave * 32;
    bf16x8 Af[2][4];
#pragma unroll
    for (int r = 0; r < 2; r++)
#pragma unroll
        for (int s = 0; s < 4; s++)
            Af[r][s] = *(const bf16x8*)(xs + (rowbase + r * 16 + ln15) * 136 + (s * 4 + quad) * 8);
    f32x4 acc[2][8];
#pragma unroll
    for (int r = 0; r < 2; r++)
#pragma unroll
        for (int t8 = 0; t8 < 8; t8++) acc[r][t8] = (f32x4){0.f, 0.f, 0.f, 0.f};
#pragma unroll
    for (int phase = 0; phase < 2; phase++) {
        const ushort* B = phase ? WqTl : WqTh;
#pragma unroll
        for (int s = 0; s < 4; s++) {
#pragma unroll
            for (int t8 = 0; t8 < 8; t8++) {
                bf16x8 b = *(const bf16x8*)(B + (t8 * 16 + ln15) * 128 + (s * 4 + quad) * 8);
                acc[0][t8] = __builtin_amdgcn_mfma_f32_16x16x32_bf16(Af[0][s], b, acc[0][t8], 0, 0, 0);
                acc[1][t8] = __builtin_amdgcn_mfma_f32_16x16x32_bf16(Af[1][s], b, acc[1][t8], 0, 0, 0);
            }
        }
    }
#pragma unroll
    for (int r = 0; r < 2; r++) {
#pragma unroll
        for (int reg = 0; reg < 4; reg++) {
            long node = nb + rowbase + r * 16 + quad * 4 + reg;
            if (node < N_NODES) {
#pragma unroll
                for (int t8 = 0; t8 < 8; t8++)
                    qaggb[node * 128 + t8 * 16 + ln15] = (ushort)bf16rne(acc[r][t8][reg]);
            }
        }
    }
}

// ================= attention (MFMA scores, chunked online softmax) + Wl GEMM =================
// grid 1563 x 256: each wave handles 16 nodes serially; per node, chunks of 16
// edges: q rows gathered straight into B-frags, 4 MFMAs give 16 scores; then
// chunk softmax + alpha-weighted x gather. xw rows staged in wave-private LDS;
// epilogue = 16x128 hi/lo MFMA GEMM with Wl + sumw*bias + lrelu -> f32 out.

__global__ __launch_bounds__(256) void attn_fin_k(
    const ushort* __restrict__ kactb, const ushort* __restrict__ qaggb,
    const ushort* __restrict__ xb, const int* __restrict__ offs,
    const int* __restrict__ deg, const int* __restrict__ scol,
    const ushort* __restrict__ WlTh, const ushort* __restrict__ WlTl,
    const float* __restrict__ bl, float* __restrict__ out) {
    __shared__ ushort xw[4][16 * 136];
    __shared__ float sws[4][16];
    int t = threadIdx.x, wave = t >> 6, lane = t & 63;
    int ln15 = lane & 15, quad = lane >> 4;
    long nb = (long)blockIdx.x * 64 + wave * 16;
    const float scale = 0.08838834764831845f;  // 1/sqrt(128)

    for (int i = 0; i < 16; i++) {
        long g = nb + i;
        int s = 0, d = 0;
        if (g < N_NODES) { s = offs[g]; d = deg[g]; }
        long gg = (g < N_NODES) ? g : 0;
        bf16x8 Af[4];
#pragma unroll
        for (int s4 = 0; s4 < 4; s4++)
            Af[s4] = *(const bf16x8*)(kactb + gg * 128 + s4 * 32 + quad * 8);

        float m = -INFINITY, S = 0.f, a0 = 0.f, a1 = 0.f;
        for (int j = 0; j < d; j += 16) {
            int lim = min(16, d - j);
            int c = (ln15 < lim) ? scol[s + j + ln15] : 0;
            f32x4 dacc = {0.f, 0.f, 0.f, 0.f};
#pragma unroll
            for (int s4 = 0; s4 < 4; s4++) {
                bf16x8 bq = *(const bf16x8*)(qaggb + (size_t)c * 128 + s4 * 32 + quad * 8);
                dacc = __builtin_amdgcn_mfma_f32_16x16x32_bf16(Af[s4], bq, dacc, 0, 0, 0);
            }
            float sc = (ln15 < lim) ? dacc[0] * scale : -INFINITY;
            float mm = sc;
#pragma unroll
            for (int off = 1; off < 16; off <<= 1) mm = fmaxf(mm, __shfl_xor(mm, off, 16));
            float mnew = fmaxf(m, mm);
            float corr = __expf(m - mnew);   // first chunk: exp(-inf)=0
            float p = __expf(sc - mnew);     // padded lanes: 0
            float ps = p;
#pragma unroll
            for (int off = 1; off < 16; off <<= 1) ps += __shfl_xor(ps, off, 16);
            S = S * corr + ps;
            a0 *= corr; a1 *= corr;
#pragma unroll
            for (int e = 0; e < 16; e++) {
                float pe = __shfl(p, e, 16);
                int ce = __shfl(c, e, 16);
                unsigned u = *(const unsigned*)(xb + (size_t)ce * 128 + lane * 2);
                a0 += pe * bflo(u);
                a1 += pe * bfhi(u);
            }
            m = mnew;
        }
        float inv = 1.f / (S + 1e-8f);
        unsigned o = bf16rne(a0 * inv) | (bf16rne(a1 * inv) << 16);
        *(unsigned*)(&xw[wave][i * 136 + lane * 2]) = o;
        if (lane == 0) sws[wave][i] = S * inv;  // sum(alpha) for exact bias
    }
    // wave-private fin GEMM: 16 rows x 128 cols (no barrier needed)
    bf16x8 Af2[4];
#pragma unroll
    for (int s4 = 0; s4 < 4; s4++)
        Af2[s4] = *(const bf16x8*)(&xw[wave][ln15 * 136 + (s4 * 4 + quad) * 8]);
    f32x4 acc2[8];
#pragma unroll
    for (int t8 = 0; t8 < 8; t8++) acc2[t8] = (f32x4){0.f, 0.f, 0.f, 0.f};
#pragma unroll
    for (int phase = 0; phase < 2; phase++) {
        const ushort* B = phase ? WlTl : WlTh;
#pragma unroll
        for (int s4 = 0; s4 < 4; s4++) {
#pragma unroll
            for (int t8 = 0; t8 < 8; t8++) {
                bf16x8 b = *(const bf16x8*)(B + (t8 * 16 + ln15) * 128 + (s4 * 4 + quad) * 8);
                acc2[t8] = __builtin_amdgcn_mfma_f32_16x16x32_bf16(Af2[s4], b, acc2[t8], 0, 0, 0);
            }
        }
    }
#pragma unroll
    for (int reg = 0; reg < 4; reg++) {
        long node = nb + quad * 4 + reg;
        if (node < N_NODES) {
            float swv = sws[wave][quad * 4 + reg];
#pragma unroll
            for (int t8 = 0; t8 < 8; t8++) {
                float v = acc2[t8][reg] + swv * bl[t8 * 16 + ln15];
                v = v > 0.f ? v : 0.2f * v;
                out[node * 128 + t8 * 16 + ln15] = v;
            }
        }
    }
}

// ================= launch =================

extern "C" void kernel_launch(void* const* d_in, const int* in_sizes, int n_in,
                              void* d_out, int out_size, void* d_ws, size_t ws_size,
                              hipStream_t stream) {
    const float* x  = (const float*)d_in[0];
    const int* row  = (const int*)d_in[1];
    const int* col  = row + N_EDGES;
    const float* Wq = (const float*)d_in[2];
    const float* Wk = (const float*)d_in[3];
    // d_in[4] = W_v: unused
    const float* Wl = (const float*)d_in[5];
    const float* bl = (const float*)d_in[6];
    float* out = (float*)d_out;

    // workspace carve (~84 MB)
    ushort* xb    = (ushort*)d_ws;                       // N*128 bf16
    ushort* kactb = xb + (size_t)N_NODES * DIM;
    ushort* qaggb = kactb + (size_t)N_NODES * DIM;
    ushort* wbuf  = qaggb + (size_t)N_NODES * DIM;       // 4 * 16384 bf16
    ushort* WqTh = wbuf,            *WqTl = wbuf + 16384;
    ushort* WlTh = wbuf + 2 * 16384, *WlTl = wbuf + 3 * 16384;
    int* deg  = (int*)(wbuf + 4 * 16384);                // N (zeroed by prep)
    int* cur  = deg + N_NODES;                           // N (zeroed by prep)
    int* offs = cur + N_NODES;                           // N
    int* scol = offs + N_NODES;                          // E

    prep_k<<<782, 256, 0, stream>>>(x, Wq, Wk, Wl, xb, kactb,
                                    WqTh, WqTl, WlTh, WlTl, deg);
    hist_k<<<N_EDGES / 256, 256, 0, stream>>>(row, deg);
    scan_k<<<1, 1024, 0, stream>>>(deg, offs);
    scatter_k<<<N_EDGES / 256, 256, 0, stream>>>(row, col, offs, cur, scol);
    xaggq_k<<<782, 256, 0, stream>>>(xb, offs, deg, scol, WqTh, WqTl, qaggb);
    attn_fin_k<<<1563, 256, 0, stream>>>(kactb, qaggb, xb, offs, deg, scol,
                                         WlTh, WlTl, bl, out);
}

// Round 5
// 580.866 us; speedup vs baseline: 1.2869x; 1.2869x over previous
//
#include <hip/hip_runtime.h>
#include <math.h>

#define N_NODES 100000
#define N_EDGES 1600000
#define DIM 128

typedef short bf16x8 __attribute__((ext_vector_type(8)));
typedef float f32x4 __attribute__((ext_vector_type(4)));

// ---- bf16 helpers (RNE pack, cheap unpack) ----
static __device__ __forceinline__ unsigned bf16rne(float f) {
    unsigned u = __float_as_uint(f);
    return (u + 0x7FFFu + ((u >> 16) & 1u)) >> 16;
}
static __device__ __forceinline__ float bflo(unsigned u) { return __uint_as_float(u << 16); }
static __device__ __forceinline__ float bfhi(unsigned u) { return __uint_as_float(u & 0xFFFF0000u); }

// ================= prep: zero deg/cur, split Wq/Wl to global, cast x->bf16,
// ================= k_act = bf16(lrelu(x @ (Wkhi+Wklo))) via MFMA =================

__global__ __launch_bounds__(256) void prep_k(
    const float* __restrict__ x, const float* __restrict__ Wq,
    const float* __restrict__ Wk, const float* __restrict__ Wl,
    ushort* __restrict__ xb, ushort* __restrict__ kactb,
    ushort* __restrict__ WqTh, ushort* __restrict__ WqTl,
    ushort* __restrict__ WlTh, ushort* __restrict__ WlTl,
    int* __restrict__ zero_base) {
    __shared__ ushort bh[128 * 136];
    __shared__ ushort blo[128 * 136];
    int t = threadIdx.x;

    // zero deg+cur (2*N ints; grid*256 = 200192 covers it)
    int zi = blockIdx.x * 256 + t;
    if (zi < 2 * N_NODES) zero_base[zi] = 0;

    // blocks 0,1: split Wq / Wl into transposed [n][k] bf16 hi/lo (global)
    if (blockIdx.x < 2) {
        const float* W = (blockIdx.x == 0) ? Wq : Wl;
        ushort* Th = (blockIdx.x == 0) ? WqTh : WlTh;
        ushort* Tl = (blockIdx.x == 0) ? WqTl : WlTl;
        for (int i = t; i < 16384; i += 256) {
            int k = i >> 7, n = i & 127;
            float v = W[i];
            unsigned hi = bf16rne(v);
            float lo = v - bflo(hi);
            Th[n * 128 + k] = (ushort)hi;
            Tl[n * 128 + k] = (ushort)bf16rne(lo);
        }
    }
    // stage WkT hi/lo in LDS (transposed, padded stride 136 shorts)
    for (int i = t; i < 16384; i += 256) {
        int k = i >> 7, n = i & 127;
        float v = Wk[i];
        unsigned hi = bf16rne(v);
        float lo = v - bflo(hi);
        bh[n * 136 + k] = (ushort)hi;
        blo[n * 136 + k] = (ushort)bf16rne(lo);
    }
    __syncthreads();

    int wave = t >> 6, lane = t & 63;
    int ln15 = lane & 15, quad = lane >> 4;
    long base = (long)blockIdx.x * 128 + wave * 32;

    bf16x8 Af[2][4];
#pragma unroll
    for (int r = 0; r < 2; r++) {
        long row = base + r * 16 + ln15;
        long rowc = row < N_NODES ? row : N_NODES - 1;
#pragma unroll
        for (int s = 0; s < 4; s++) {
            int ch = s * 4 + quad;  // 8-feat chunk index
            const float4* xp = (const float4*)(x + rowc * 128 + ch * 8);
            float4 u0 = xp[0], u1 = xp[1];
            bf16x8 f;
            f[0] = (short)bf16rne(u0.x); f[1] = (short)bf16rne(u0.y);
            f[2] = (short)bf16rne(u0.z); f[3] = (short)bf16rne(u0.w);
            f[4] = (short)bf16rne(u1.x); f[5] = (short)bf16rne(u1.y);
            f[6] = (short)bf16rne(u1.z); f[7] = (short)bf16rne(u1.w);
            Af[r][s] = f;
            if (row < N_NODES) *(bf16x8*)(xb + row * 128 + ch * 8) = f;
        }
    }
    f32x4 acc[2][8];
#pragma unroll
    for (int r = 0; r < 2; r++)
#pragma unroll
        for (int t8 = 0; t8 < 8; t8++) acc[r][t8] = (f32x4){0.f, 0.f, 0.f, 0.f};
#pragma unroll
    for (int phase = 0; phase < 2; phase++) {
        const ushort* B = phase ? blo : bh;
#pragma unroll
        for (int s = 0; s < 4; s++) {
#pragma unroll
            for (int t8 = 0; t8 < 8; t8++) {
                bf16x8 b = *(const bf16x8*)(B + (t8 * 16 + ln15) * 136 + (s * 4 + quad) * 8);
                acc[0][t8] = __builtin_amdgcn_mfma_f32_16x16x32_bf16(Af[0][s], b, acc[0][t8], 0, 0, 0);
                acc[1][t8] = __builtin_amdgcn_mfma_f32_16x16x32_bf16(Af[1][s], b, acc[1][t8], 0, 0, 0);
            }
        }
    }
#pragma unroll
    for (int r = 0; r < 2; r++) {
#pragma unroll
        for (int reg = 0; reg < 4; reg++) {
            long node = base + r * 16 + quad * 4 + reg;
            if (node < N_NODES) {
#pragma unroll
                for (int t8 = 0; t8 < 8; t8++) {
                    float v = acc[r][t8][reg];
                    v = v > 0.f ? v : 0.2f * v;
                    kactb[node * 128 + t8 * 16 + ln15] = (ushort)bf16rne(v);
                }
            }
        }
    }
}

// ================= CSR build =================

__global__ void hist_k(const int* __restrict__ row, int* __restrict__ deg) {
    int e = blockIdx.x * 256 + threadIdx.x;
    if (e < N_EDGES) atomicAdd(&deg[row[e]], 1);
}

__global__ __launch_bounds__(1024) void scan_k(const int* __restrict__ deg,
                                               int* __restrict__ offs) {
    __shared__ int wsum[16];
    __shared__ int carry_s;
    int t = threadIdx.x, wid = t >> 6, lane = t & 63;
    if (t == 0) carry_s = 0;
    __syncthreads();
    const int4* d4 = (const int4*)deg;   // N/4 = 25000
    int4* o4 = (int4*)offs;
    for (int base4 = 0; base4 < 25000; base4 += 2048) {
        int i0 = base4 + t * 2, i1 = i0 + 1;
        int4 z4 = {0, 0, 0, 0};
        int4 va = (i0 < 25000) ? d4[i0] : z4;
        int4 vb = (i1 < 25000) ? d4[i1] : z4;
        int e1 = va.x, e2 = e1 + va.y, e3 = e2 + va.z, e4 = e3 + va.w;
        int e5 = e4 + vb.x, e6 = e5 + vb.y, e7 = e6 + vb.z, s = e7 + vb.w;
        int incl = s;
#pragma unroll
        for (int off = 1; off < 64; off <<= 1) {
            int y = __shfl_up(incl, off, 64);
            if (lane >= off) incl += y;
        }
        if (lane == 63) wsum[wid] = incl;
        __syncthreads();
        if (t < 16) {
            int w = wsum[t];
            int wi = w;
#pragma unroll
            for (int off = 1; off < 16; off <<= 1) {
                int y = __shfl_up(wi, off, 64);
                if (t >= off) wi += y;
            }
            wsum[t] = wi - w;  // exclusive wave prefix
        }
        __syncthreads();
        int excl = carry_s + wsum[wid] + incl - s;
        int4 oa = {excl, excl + e1, excl + e2, excl + e3};
        int4 ob = {excl + e4, excl + e5, excl + e6, excl + e7};
        if (i0 < 25000) o4[i0] = oa;
        if (i1 < 25000) o4[i1] = ob;
        __syncthreads();
        if (t == 1023) carry_s = excl + s;
        __syncthreads();
    }
}

__global__ void scatter_k(const int* __restrict__ row, const int* __restrict__ col,
                          const int* __restrict__ offs, int* __restrict__ cur,
                          int* __restrict__ scol) {
    int e = blockIdx.x * 256 + threadIdx.x;
    if (e < N_EDGES) {
        int r = row[e];
        int p = offs[r] + atomicAdd(&cur[r], 1);
        scol[p] = col[e];
    }
}

// ================= pass A: x_agg gather (bf16), 4-way ILP =================
// 32 lanes/node, uint2 (4 feats)/lane, no LDS, low VGPR -> high occupancy.

__global__ __launch_bounds__(256) void xagg_k(const uint2* __restrict__ xb,
                                              const int* __restrict__ offs,
                                              const int* __restrict__ deg,
                                              const int* __restrict__ scol,
                                              uint2* __restrict__ xaggb) {
    int g = (blockIdx.x * 256 + threadIdx.x) >> 5;  // node id (grid exact)
    int lane = threadIdx.x & 31;
    int s = offs[g], d = deg[g];
    float a0 = 0.f, a1 = 0.f, a2 = 0.f, a3 = 0.f;      // slot 0
    float b0 = 0.f, b1 = 0.f, b2 = 0.f, b3 = 0.f;      // slot 1
    float c0f = 0.f, c1f = 0.f, c2f = 0.f, c3f = 0.f;  // slot 2
    float d0 = 0.f, d1 = 0.f, d2 = 0.f, d3 = 0.f;      // slot 3
    for (int j = 0; j < d; j += 32) {
        int cb = (j + lane < d) ? scol[s + j + lane] : 0;
        int lim = min(32, d - j);
        int k = 0;
        for (; k + 4 <= lim; k += 4) {
            int c0 = __shfl(cb, k, 32),     c1 = __shfl(cb, k + 1, 32);
            int c2 = __shfl(cb, k + 2, 32), c3 = __shfl(cb, k + 3, 32);
            uint2 u0 = xb[(size_t)c0 * 32 + lane];
            uint2 u1 = xb[(size_t)c1 * 32 + lane];
            uint2 u2 = xb[(size_t)c2 * 32 + lane];
            uint2 u3 = xb[(size_t)c3 * 32 + lane];
            a0 += bflo(u0.x); a1 += bfhi(u0.x); a2 += bflo(u0.y); a3 += bfhi(u0.y);
            b0 += bflo(u1.x); b1 += bfhi(u1.x); b2 += bflo(u1.y); b3 += bfhi(u1.y);
            c0f += bflo(u2.x); c1f += bfhi(u2.x); c2f += bflo(u2.y); c3f += bfhi(u2.y);
            d0 += bflo(u3.x); d1 += bfhi(u3.x); d2 += bflo(u3.y); d3 += bfhi(u3.y);
        }
        for (; k < lim; k++) {
            int c = __shfl(cb, k, 32);
            uint2 u = xb[(size_t)c * 32 + lane];
            a0 += bflo(u.x); a1 += bfhi(u.x); a2 += bflo(u.y); a3 += bfhi(u.y);
        }
    }
    a0 += b0 + c0f + d0; a1 += b1 + c1f + d1;
    a2 += b2 + c2f + d2; a3 += b3 + c3f + d3;
    uint2 o;
    o.x = bf16rne(a0) | (bf16rne(a1) << 16);
    o.y = bf16rne(a2) | (bf16rne(a3) << 16);
    xaggb[(size_t)g * 32 + lane] = o;
}

// ================= MFMA GEMM: D = bf16(A @ (Whi+Wlo)), in-place safe =================

__global__ __launch_bounds__(256) void mgemm_k(const ushort* __restrict__ Ab,
                                               const ushort* __restrict__ BTh,
                                               const ushort* __restrict__ BTl,
                                               ushort* __restrict__ Db) {
    int tid = threadIdx.x;
    int wave = tid >> 6, lane = tid & 63;
    int ln15 = lane & 15, quad = (lane >> 4) & 3;
    long base = (long)blockIdx.x * 128 + wave * 32;

    const bf16x8* A8 = (const bf16x8*)Ab;
    const bf16x8* Bh8 = (const bf16x8*)BTh;
    const bf16x8* Bl8 = (const bf16x8*)BTl;

    bf16x8 Af[2][4];
#pragma unroll
    for (int r = 0; r < 2; r++) {
        long row = base + r * 16 + ln15;
#pragma unroll
        for (int s = 0; s < 4; s++) Af[r][s] = A8[row * 16 + s * 4 + quad];
    }
    f32x4 acc[2][8];
#pragma unroll
    for (int r = 0; r < 2; r++)
#pragma unroll
        for (int t = 0; t < 8; t++) acc[r][t] = (f32x4){0.f, 0.f, 0.f, 0.f};

#pragma unroll
    for (int phase = 0; phase < 2; phase++) {
        const bf16x8* B8 = phase ? Bl8 : Bh8;
#pragma unroll
        for (int s = 0; s < 4; s++) {
#pragma unroll
            for (int t = 0; t < 8; t++) {
                bf16x8 b = B8[(t * 16 + ln15) * 16 + s * 4 + quad];
                acc[0][t] = __builtin_amdgcn_mfma_f32_16x16x32_bf16(Af[0][s], b, acc[0][t], 0, 0, 0);
                acc[1][t] = __builtin_amdgcn_mfma_f32_16x16x32_bf16(Af[1][s], b, acc[1][t], 0, 0, 0);
            }
        }
    }
#pragma unroll
    for (int r = 0; r < 2; r++) {
#pragma unroll
        for (int reg = 0; reg < 4; reg++) {
            long node = base + r * 16 + quad * 4 + reg;
            if (node < N_NODES) {
#pragma unroll
                for (int t = 0; t < 8; t++)
                    Db[node * 128 + t * 16 + ln15] = (ushort)bf16rne(acc[r][t][reg]);
            }
        }
    }
}

// ================= pass B: online-softmax attention, 2-way ILP, branch-free =================

__global__ __launch_bounds__(256) void attn_k(const uint2* __restrict__ kactb,
                                              const uint2* __restrict__ qaggb,
                                              const uint2* __restrict__ xb,
                                              const int* __restrict__ offs,
                                              const int* __restrict__ deg,
                                              const int* __restrict__ scol,
                                              uint2* __restrict__ xwb,
                                              float* __restrict__ sumw) {
    int g = (blockIdx.x * 256 + threadIdx.x) >> 5;
    int lane = threadIdx.x & 31;
    int s = offs[g], d = deg[g];
    uint2 ku = kactb[(size_t)g * 32 + lane];
    float k0 = bflo(ku.x), k1 = bfhi(ku.x), k2 = bflo(ku.y), k3 = bfhi(ku.y);
    const float scale = 0.08838834764831845f;  // 1/sqrt(128)

    float m = -INFINITY, S = 0.f;
    float a0 = 0.f, a1 = 0.f, a2 = 0.f, a3 = 0.f;
    for (int j = 0; j < d; j += 32) {
        int cb = (j + lane < d) ? scol[s + j + lane] : 0;
        int lim = min(32, d - j);
        int k = 0;
        for (; k + 2 <= lim; k += 2) {
            int c0 = __shfl(cb, k, 32), c1 = __shfl(cb, k + 1, 32);
            uint2 q0 = qaggb[(size_t)c0 * 32 + lane];
            uint2 x0 = xb[(size_t)c0 * 32 + lane];
            uint2 q1 = qaggb[(size_t)c1 * 32 + lane];
            uint2 x1 = xb[(size_t)c1 * 32 + lane];
            float p0 = k0 * bflo(q0.x) + k1 * bfhi(q0.x) + k2 * bflo(q0.y) + k3 * bfhi(q0.y);
            float p1 = k0 * bflo(q1.x) + k1 * bfhi(q1.x) + k2 * bflo(q1.y) + k3 * bfhi(q1.y);
#pragma unroll
            for (int off = 16; off > 0; off >>= 1) {
                p0 += __shfl_xor(p0, off);
                p1 += __shfl_xor(p1, off);
            }
            float s0 = p0 * scale, s1 = p1 * scale;
            float mnew = fmaxf(m, fmaxf(s0, s1));
            float corr = __expf(m - mnew);       // first pair: exp(-inf)=0
            float e0 = __expf(s0 - mnew);
            float e1 = __expf(s1 - mnew);
            S = S * corr + e0 + e1;
            a0 = a0 * corr + e0 * bflo(x0.x) + e1 * bflo(x1.x);
            a1 = a1 * corr + e0 * bfhi(x0.x) + e1 * bfhi(x1.x);
            a2 = a2 * corr + e0 * bflo(x0.y) + e1 * bflo(x1.y);
            a3 = a3 * corr + e0 * bfhi(x0.y) + e1 * bfhi(x1.y);
            m = mnew;
        }
        for (; k < lim; k++) {
            int c = __shfl(cb, k, 32);
            uint2 qu = qaggb[(size_t)c * 32 + lane];
            uint2 xu = xb[(size_t)c * 32 + lane];
            float p = k0 * bflo(qu.x) + k1 * bfhi(qu.x) + k2 * bflo(qu.y) + k3 * bfhi(qu.y);
#pragma unroll
            for (int off = 16; off > 0; off >>= 1) p += __shfl_xor(p, off);
            float sc = p * scale;
            float mnew = fmaxf(m, sc);
            float corr = __expf(m - mnew);
            float e0 = __expf(sc - mnew);
            S = S * corr + e0;
            a0 = a0 * corr + e0 * bflo(xu.x);
            a1 = a1 * corr + e0 * bfhi(xu.x);
            a2 = a2 * corr + e0 * bflo(xu.y);
            a3 = a3 * corr + e0 * bfhi(xu.y);
            m = mnew;
        }
    }
    float inv = 1.f / (S + 1e-8f);
    uint2 o;
    o.x = bf16rne(a0 * inv) | (bf16rne(a1 * inv) << 16);
    o.y = bf16rne(a2 * inv) | (bf16rne(a3 * inv) << 16);
    xwb[(size_t)g * 32 + lane] = o;
    if (lane == 0) sumw[g] = S * inv;  // sum(alpha) for exact bias term
}

// ================= final MFMA GEMM: out = lrelu(xw @ Wl + sumw*b), f32 out =================

__global__ __launch_bounds__(256) void fin_k(const ushort* __restrict__ Ab,
                                             const ushort* __restrict__ BTh,
                                             const ushort* __restrict__ BTl,
                                             const float* __restrict__ bl,
                                             const float* __restrict__ sumw,
                                             float* __restrict__ out) {
    int tid = threadIdx.x;
    int wave = tid >> 6, lane = tid & 63;
    int ln15 = lane & 15, quad = (lane >> 4) & 3;
    long base = (long)blockIdx.x * 128 + wave * 32;

    const bf16x8* A8 = (const bf16x8*)Ab;
    const bf16x8* Bh8 = (const bf16x8*)BTh;
    const bf16x8* Bl8 = (const bf16x8*)BTl;

    bf16x8 Af[2][4];
#pragma unroll
    for (int r = 0; r < 2; r++) {
        long row = base + r * 16 + ln15;
#pragma unroll
        for (int s = 0; s < 4; s++) Af[r][s] = A8[row * 16 + s * 4 + quad];
    }
    float blv[8];
#pragma unroll
    for (int t = 0; t < 8; t++) blv[t] = bl[t * 16 + ln15];

    f32x4 acc[2][8];
#pragma unroll
    for (int r = 0; r < 2; r++)
#pragma unroll
        for (int t = 0; t < 8; t++) acc[r][t] = (f32x4){0.f, 0.f, 0.f, 0.f};

#pragma unroll
    for (int phase = 0; phase < 2; phase++) {
        const bf16x8* B8 = phase ? Bl8 : Bh8;
#pragma unroll
        for (int s = 0; s < 4; s++) {
#pragma unroll
            for (int t = 0; t < 8; t++) {
                bf16x8 b = B8[(t * 16 + ln15) * 16 + s * 4 + quad];
                acc[0][t] = __builtin_amdgcn_mfma_f32_16x16x32_bf16(Af[0][s], b, acc[0][t], 0, 0, 0);
                acc[1][t] = __builtin_amdgcn_mfma_f32_16x16x32_bf16(Af[1][s], b, acc[1][t], 0, 0, 0);
            }
        }
    }
#pragma unroll
    for (int r = 0; r < 2; r++) {
#pragma unroll
        for (int reg = 0; reg < 4; reg++) {
            long node = base + r * 16 + quad * 4 + reg;
            if (node < N_NODES) {
                float sw = sumw[node];
#pragma unroll
                for (int t = 0; t < 8; t++) {
                    float v = acc[r][t][reg] + sw * blv[t];
                    v = v > 0.f ? v : 0.2f * v;
                    out[node * 128 + t * 16 + ln15] = v;
                }
            }
        }
    }
}

// ================= launch =================

extern "C" void kernel_launch(void* const* d_in, const int* in_sizes, int n_in,
                              void* d_out, int out_size, void* d_ws, size_t ws_size,
                              hipStream_t stream) {
    const float* x  = (const float*)d_in[0];
    const int* row  = (const int*)d_in[1];
    const int* col  = row + N_EDGES;
    const float* Wq = (const float*)d_in[2];
    const float* Wk = (const float*)d_in[3];
    // d_in[4] = W_v: unused
    const float* Wl = (const float*)d_in[5];
    const float* bl = (const float*)d_in[6];
    float* out = (float*)d_out;

    // workspace carve (~110 MB). Order matters: MFMA A-loads overread <=96 rows
    // past xaggb/xwb; both are followed by valid arrays.
    ushort* xb    = (ushort*)d_ws;                       // N*128 bf16
    ushort* xaggb = xb + (size_t)N_NODES * DIM;          // qagg in-place (block-local)
    ushort* kactb = xaggb + (size_t)N_NODES * DIM;
    ushort* xwb   = kactb + (size_t)N_NODES * DIM;
    ushort* wbuf  = xwb + (size_t)N_NODES * DIM;         // 4 * 16384 bf16
    ushort* WqTh = wbuf,             *WqTl = wbuf + 16384;
    ushort* WlTh = wbuf + 2 * 16384, *WlTl = wbuf + 3 * 16384;
    float* sumw = (float*)(wbuf + 4 * 16384);            // N f32
    int* deg  = (int*)(sumw + N_NODES);                  // N (zeroed by prep)
    int* cur  = deg + N_NODES;                           // N (zeroed by prep, adjacent)
    int* offs = cur + N_NODES;                           // N
    int* scol = offs + N_NODES;                          // E

    prep_k<<<782, 256, 0, stream>>>(x, Wq, Wk, Wl, xb, kactb,
                                    WqTh, WqTl, WlTh, WlTl, deg);
    hist_k<<<N_EDGES / 256, 256, 0, stream>>>(row, deg);
    scan_k<<<1, 1024, 0, stream>>>(deg, offs);
    scatter_k<<<N_EDGES / 256, 256, 0, stream>>>(row, col, offs, cur, scol);
    xagg_k<<<N_NODES / 8, 256, 0, stream>>>((const uint2*)xb, offs, deg, scol,
                                            (uint2*)xaggb);
    mgemm_k<<<(N_NODES + 127) / 128, 256, 0, stream>>>(xaggb, WqTh, WqTl, xaggb);
    attn_k<<<N_NODES / 8, 256, 0, stream>>>((const uint2*)kactb, (const uint2*)xaggb,
                                            (const uint2*)xb, offs, deg, scol,
                                            (uint2*)xwb, sumw);
    fin_k<<<(N_NODES + 127) / 128, 256, 0, stream>>>(xwb, WlTh, WlTl, bl, sumw, out);
}

// Round 6
// 554.615 us; speedup vs baseline: 1.3478x; 1.0473x over previous
//
#include <hip/hip_runtime.h>
#include <math.h>

#define N_NODES 100000
#define N_EDGES 1600000
#define DIM 128
#define CAP 64  // per-node edge bucket capacity; deg ~ Poisson(16), P(>64) ~ 1e-12

typedef short bf16x8 __attribute__((ext_vector_type(8)));
typedef float f32x4 __attribute__((ext_vector_type(4)));

// ---- bf16 helpers (RNE pack, cheap unpack) ----
static __device__ __forceinline__ unsigned bf16rne(float f) {
    unsigned u = __float_as_uint(f);
    return (u + 0x7FFFu + ((u >> 16) & 1u)) >> 16;
}
static __device__ __forceinline__ float bflo(unsigned u) { return __uint_as_float(u << 16); }
static __device__ __forceinline__ float bfhi(unsigned u) { return __uint_as_float(u & 0xFFFF0000u); }

// ================= prep: zero cur, split Wq/Wl, cast x->bf16 (xb + qx x-half),
// ================= k_act = bf16(lrelu(x @ (Wkhi+Wklo))) via MFMA =================

__global__ __launch_bounds__(256) void prep_k(
    const float* __restrict__ x, const float* __restrict__ Wq,
    const float* __restrict__ Wk, const float* __restrict__ Wl,
    ushort* __restrict__ xb, ushort* __restrict__ qx, ushort* __restrict__ kactb,
    ushort* __restrict__ WqTh, ushort* __restrict__ WqTl,
    ushort* __restrict__ WlTh, ushort* __restrict__ WlTl,
    int* __restrict__ cur) {
    __shared__ ushort bh[128 * 136];
    __shared__ ushort blo[128 * 136];
    int t = threadIdx.x;

    int zi = blockIdx.x * 256 + t;
    if (zi < N_NODES) cur[zi] = 0;

    if (blockIdx.x < 2) {
        const float* W = (blockIdx.x == 0) ? Wq : Wl;
        ushort* Th = (blockIdx.x == 0) ? WqTh : WlTh;
        ushort* Tl = (blockIdx.x == 0) ? WqTl : WlTl;
        for (int i = t; i < 16384; i += 256) {
            int k = i >> 7, n = i & 127;
            float v = W[i];
            unsigned hi = bf16rne(v);
            float lo = v - bflo(hi);
            Th[n * 128 + k] = (ushort)hi;
            Tl[n * 128 + k] = (ushort)bf16rne(lo);
        }
    }
    for (int i = t; i < 16384; i += 256) {
        int k = i >> 7, n = i & 127;
        float v = Wk[i];
        unsigned hi = bf16rne(v);
        float lo = v - bflo(hi);
        bh[n * 136 + k] = (ushort)hi;
        blo[n * 136 + k] = (ushort)bf16rne(lo);
    }
    __syncthreads();

    int wave = t >> 6, lane = t & 63;
    int ln15 = lane & 15, quad = lane >> 4;
    long base = (long)blockIdx.x * 128 + wave * 32;

    bf16x8 Af[2][4];
#pragma unroll
    for (int r = 0; r < 2; r++) {
        long row = base + r * 16 + ln15;
        long rowc = row < N_NODES ? row : N_NODES - 1;
#pragma unroll
        for (int s = 0; s < 4; s++) {
            int ch = s * 4 + quad;  // 8-feat chunk index (0..15)
            const float4* xp = (const float4*)(x + rowc * 128 + ch * 8);
            float4 u0 = xp[0], u1 = xp[1];
            bf16x8 f;
            f[0] = (short)bf16rne(u0.x); f[1] = (short)bf16rne(u0.y);
            f[2] = (short)bf16rne(u0.z); f[3] = (short)bf16rne(u0.w);
            f[4] = (short)bf16rne(u1.x); f[5] = (short)bf16rne(u1.y);
            f[6] = (short)bf16rne(u1.z); f[7] = (short)bf16rne(u1.w);
            Af[r][s] = f;
            if (row < N_NODES) {
                *(bf16x8*)(xb + row * 128 + ch * 8) = f;
                // interleaved qx x-half: feat f -> row*256 + (f>>2)*8 + 4 + (f&3)
                uint4 fu = *(uint4*)&f;
                *(uint2*)(qx + row * 256 + 16 * ch + 4)  = make_uint2(fu.x, fu.y);
                *(uint2*)(qx + row * 256 + 16 * ch + 12) = make_uint2(fu.z, fu.w);
            }
        }
    }
    f32x4 acc[2][8];
#pragma unroll
    for (int r = 0; r < 2; r++)
#pragma unroll
        for (int t8 = 0; t8 < 8; t8++) acc[r][t8] = (f32x4){0.f, 0.f, 0.f, 0.f};
#pragma unroll
    for (int phase = 0; phase < 2; phase++) {
        const ushort* B = phase ? blo : bh;
#pragma unroll
        for (int s = 0; s < 4; s++) {
#pragma unroll
            for (int t8 = 0; t8 < 8; t8++) {
                bf16x8 b = *(const bf16x8*)(B + (t8 * 16 + ln15) * 136 + (s * 4 + quad) * 8);
                acc[0][t8] = __builtin_amdgcn_mfma_f32_16x16x32_bf16(Af[0][s], b, acc[0][t8], 0, 0, 0);
                acc[1][t8] = __builtin_amdgcn_mfma_f32_16x16x32_bf16(Af[1][s], b, acc[1][t8], 0, 0, 0);
            }
        }
    }
#pragma unroll
    for (int r = 0; r < 2; r++) {
#pragma unroll
        for (int reg = 0; reg < 4; reg++) {
            long node = base + r * 16 + quad * 4 + reg;
            if (node < N_NODES) {
#pragma unroll
                for (int t8 = 0; t8 < 8; t8++) {
                    float v = acc[r][t8][reg];
                    v = v > 0.f ? v : 0.2f * v;
                    kactb[node * 128 + t8 * 16 + ln15] = (ushort)bf16rne(v);
                }
            }
        }
    }
}

// ================= bucket scatter (no hist/scan needed; cur ends as degree) =================

__global__ void scatter_k(const int* __restrict__ row, const int* __restrict__ col,
                          int* __restrict__ cur, int* __restrict__ scol) {
    int e = blockIdx.x * 256 + threadIdx.x;  // grid exact
    int r = row[e];
    int p = atomicAdd(&cur[r], 1);
    if (p < CAP) scol[r * CAP + p] = col[e];
}

// ================= pass A: x_agg gather, 16 lanes/node, uint4 loads, 4-way ILP =================

__global__ __launch_bounds__(256) void xagg_k(const uint4* __restrict__ xb4,
                                              const int* __restrict__ cur,
                                              const int* __restrict__ scol,
                                              uint4* __restrict__ xagg4) {
    int g = (blockIdx.x * 256 + threadIdx.x) >> 4;  // node id (grid exact)
    int gl = threadIdx.x & 15;
    int d = min(cur[g], CAP);
    float a0 = 0.f, a1 = 0.f, a2 = 0.f, a3 = 0.f;
    float a4 = 0.f, a5 = 0.f, a6 = 0.f, a7 = 0.f;
    for (int j = 0; j < d; j += 16) {
        int cb = (j + gl < d) ? scol[g * CAP + j + gl] : 0;
        int lim = min(16, d - j);
        int k = 0;
        for (; k + 4 <= lim; k += 4) {
            int c0 = __shfl(cb, k, 16),     c1 = __shfl(cb, k + 1, 16);
            int c2 = __shfl(cb, k + 2, 16), c3 = __shfl(cb, k + 3, 16);
            uint4 u0 = xb4[(size_t)c0 * 16 + gl];
            uint4 u1 = xb4[(size_t)c1 * 16 + gl];
            uint4 u2 = xb4[(size_t)c2 * 16 + gl];
            uint4 u3 = xb4[(size_t)c3 * 16 + gl];
            a0 += bflo(u0.x); a1 += bfhi(u0.x); a2 += bflo(u0.y); a3 += bfhi(u0.y);
            a4 += bflo(u0.z); a5 += bfhi(u0.z); a6 += bflo(u0.w); a7 += bfhi(u0.w);
            a0 += bflo(u1.x); a1 += bfhi(u1.x); a2 += bflo(u1.y); a3 += bfhi(u1.y);
            a4 += bflo(u1.z); a5 += bfhi(u1.z); a6 += bflo(u1.w); a7 += bfhi(u1.w);
            a0 += bflo(u2.x); a1 += bfhi(u2.x); a2 += bflo(u2.y); a3 += bfhi(u2.y);
            a4 += bflo(u2.z); a5 += bfhi(u2.z); a6 += bflo(u2.w); a7 += bfhi(u2.w);
            a0 += bflo(u3.x); a1 += bfhi(u3.x); a2 += bflo(u3.y); a3 += bfhi(u3.y);
            a4 += bflo(u3.z); a5 += bfhi(u3.z); a6 += bflo(u3.w); a7 += bfhi(u3.w);
        }
        for (; k < lim; k++) {
            int c = __shfl(cb, k, 16);
            uint4 u = xb4[(size_t)c * 16 + gl];
            a0 += bflo(u.x); a1 += bfhi(u.x); a2 += bflo(u.y); a3 += bfhi(u.y);
            a4 += bflo(u.z); a5 += bfhi(u.z); a6 += bflo(u.w); a7 += bfhi(u.w);
        }
    }
    uint4 o;
    o.x = bf16rne(a0) | (bf16rne(a1) << 16);
    o.y = bf16rne(a2) | (bf16rne(a3) << 16);
    o.z = bf16rne(a4) | (bf16rne(a5) << 16);
    o.w = bf16rne(a6) | (bf16rne(a7) << 16);
    xagg4[(size_t)g * 16 + gl] = o;
}

// ================= MFMA GEMM: q = bf16(xagg @ (Wqhi+Wqlo)) -> interleaved qx =================

__global__ __launch_bounds__(256) void mgemm_k(const ushort* __restrict__ Ab,
                                               const ushort* __restrict__ BTh,
                                               const ushort* __restrict__ BTl,
                                               ushort* __restrict__ qx) {
    int tid = threadIdx.x;
    int wave = tid >> 6, lane = tid & 63;
    int ln15 = lane & 15, quad = (lane >> 4) & 3;
    long base = (long)blockIdx.x * 128 + wave * 32;

    const bf16x8* A8 = (const bf16x8*)Ab;
    const bf16x8* Bh8 = (const bf16x8*)BTh;
    const bf16x8* Bl8 = (const bf16x8*)BTl;

    bf16x8 Af[2][4];
#pragma unroll
    for (int r = 0; r < 2; r++) {
        long row = base + r * 16 + ln15;
#pragma unroll
        for (int s = 0; s < 4; s++) Af[r][s] = A8[row * 16 + s * 4 + quad];
    }
    f32x4 acc[2][8];
#pragma unroll
    for (int r = 0; r < 2; r++)
#pragma unroll
        for (int t = 0; t < 8; t++) acc[r][t] = (f32x4){0.f, 0.f, 0.f, 0.f};

#pragma unroll
    for (int phase = 0; phase < 2; phase++) {
        const bf16x8* B8 = phase ? Bl8 : Bh8;
#pragma unroll
        for (int s = 0; s < 4; s++) {
#pragma unroll
            for (int t = 0; t < 8; t++) {
                bf16x8 b = B8[(t * 16 + ln15) * 16 + s * 4 + quad];
                acc[0][t] = __builtin_amdgcn_mfma_f32_16x16x32_bf16(Af[0][s], b, acc[0][t], 0, 0, 0);
                acc[1][t] = __builtin_amdgcn_mfma_f32_16x16x32_bf16(Af[1][s], b, acc[1][t], 0, 0, 0);
            }
        }
    }
    // interleaved store: q feat j -> node*256 + (j>>2)*8 + (j&3)
#pragma unroll
    for (int r = 0; r < 2; r++) {
#pragma unroll
        for (int reg = 0; reg < 4; reg++) {
            long node = base + r * 16 + quad * 4 + reg;
            if (node < N_NODES) {
#pragma unroll
                for (int t = 0; t < 8; t++) {
                    int j = t * 16 + ln15;
                    qx[node * 256 + (j >> 2) * 8 + (j & 3)] = (ushort)bf16rne(acc[r][t][reg]);
                }
            }
        }
    }
}

// ================= pass B: online-softmax attention, single uint4 gather/edge =================

__global__ __launch_bounds__(256) void attn_k(const uint2* __restrict__ kactb,
                                              const uint4* __restrict__ qx4,
                                              const int* __restrict__ cur,
                                              const int* __restrict__ scol,
                                              uint2* __restrict__ xwb,
                                              float* __restrict__ sumw) {
    int g = (blockIdx.x * 256 + threadIdx.x) >> 5;  // node id (grid exact)
    int lane = threadIdx.x & 31;
    int d = min(cur[g], CAP);
    uint2 ku = kactb[(size_t)g * 32 + lane];
    float k0 = bflo(ku.x), k1 = bfhi(ku.x), k2 = bflo(ku.y), k3 = bfhi(ku.y);
    const float scale = 0.08838834764831845f;  // 1/sqrt(128)

    float m = -INFINITY, S = 0.f;
    float a0 = 0.f, a1 = 0.f, a2 = 0.f, a3 = 0.f;
    for (int j = 0; j < d; j += 32) {
        int cb = (j + lane < d) ? scol[g * CAP + j + lane] : 0;
        int lim = min(32, d - j);
        int k = 0;
        for (; k + 2 <= lim; k += 2) {
            int c0 = __shfl(cb, k, 32), c1 = __shfl(cb, k + 1, 32);
            uint4 u0 = qx4[(size_t)c0 * 32 + lane];
            uint4 u1 = qx4[(size_t)c1 * 32 + lane];
            float p0 = k0 * bflo(u0.x) + k1 * bfhi(u0.x) + k2 * bflo(u0.y) + k3 * bfhi(u0.y);
            float p1 = k0 * bflo(u1.x) + k1 * bfhi(u1.x) + k2 * bflo(u1.y) + k3 * bfhi(u1.y);
#pragma unroll
            for (int off = 16; off > 0; off >>= 1) {
                p0 += __shfl_xor(p0, off);
                p1 += __shfl_xor(p1, off);
            }
            float s0 = p0 * scale, s1 = p1 * scale;
            float mnew = fmaxf(m, fmaxf(s0, s1));
            float corr = __expf(m - mnew);       // first pair: exp(-inf)=0
            float e0 = __expf(s0 - mnew);
            float e1 = __expf(s1 - mnew);
            S = S * corr + e0 + e1;
            a0 = a0 * corr + e0 * bflo(u0.z) + e1 * bflo(u1.z);
            a1 = a1 * corr + e0 * bfhi(u0.z) + e1 * bfhi(u1.z);
            a2 = a2 * corr + e0 * bflo(u0.w) + e1 * bflo(u1.w);
            a3 = a3 * corr + e0 * bfhi(u0.w) + e1 * bfhi(u1.w);
            m = mnew;
        }
        for (; k < lim; k++) {
            int c = __shfl(cb, k, 32);
            uint4 u = qx4[(size_t)c * 32 + lane];
            float p = k0 * bflo(u.x) + k1 * bfhi(u.x) + k2 * bflo(u.y) + k3 * bfhi(u.y);
#pragma unroll
            for (int off = 16; off > 0; off >>= 1) p += __shfl_xor(p, off);
            float sc = p * scale;
            float mnew = fmaxf(m, sc);
            float corr = __expf(m - mnew);
            float e0 = __expf(sc - mnew);
            S = S * corr + e0;
            a0 = a0 * corr + e0 * bflo(u.z);
            a1 = a1 * corr + e0 * bfhi(u.z);
            a2 = a2 * corr + e0 * bflo(u.w);
            a3 = a3 * corr + e0 * bfhi(u.w);
            m = mnew;
        }
    }
    float inv = 1.f / (S + 1e-8f);
    uint2 o;
    o.x = bf16rne(a0 * inv) | (bf16rne(a1 * inv) << 16);
    o.y = bf16rne(a2 * inv) | (bf16rne(a3 * inv) << 16);
    xwb[(size_t)g * 32 + lane] = o;
    if (lane == 0) sumw[g] = S * inv;  // sum(alpha) for exact bias term
}

// ================= final MFMA GEMM: out = lrelu(xw @ Wl + sumw*b), f32 out =================

__global__ __launch_bounds__(256) void fin_k(const ushort* __restrict__ Ab,
                                             const ushort* __restrict__ BTh,
                                             const ushort* __restrict__ BTl,
                                             const float* __restrict__ bl,
                                             const float* __restrict__ sumw,
                                             float* __restrict__ out) {
    int tid = threadIdx.x;
    int wave = tid >> 6, lane = tid & 63;
    int ln15 = lane & 15, quad = (lane >> 4) & 3;
    long base = (long)blockIdx.x * 128 + wave * 32;

    const bf16x8* A8 = (const bf16x8*)Ab;
    const bf16x8* Bh8 = (const bf16x8*)BTh;
    const bf16x8* Bl8 = (const bf16x8*)BTl;

    bf16x8 Af[2][4];
#pragma unroll
    for (int r = 0; r < 2; r++) {
        long row = base + r * 16 + ln15;
#pragma unroll
        for (int s = 0; s < 4; s++) Af[r][s] = A8[row * 16 + s * 4 + quad];
    }
    float blv[8];
#pragma unroll
    for (int t = 0; t < 8; t++) blv[t] = bl[t * 16 + ln15];

    f32x4 acc[2][8];
#pragma unroll
    for (int r = 0; r < 2; r++)
#pragma unroll
        for (int t = 0; t < 8; t++) acc[r][t] = (f32x4){0.f, 0.f, 0.f, 0.f};

#pragma unroll
    for (int phase = 0; phase < 2; phase++) {
        const bf16x8* B8 = phase ? Bl8 : Bh8;
#pragma unroll
        for (int s = 0; s < 4; s++) {
#pragma unroll
            for (int t = 0; t < 8; t++) {
                bf16x8 b = B8[(t * 16 + ln15) * 16 + s * 4 + quad];
                acc[0][t] = __builtin_amdgcn_mfma_f32_16x16x32_bf16(Af[0][s], b, acc[0][t], 0, 0, 0);
                acc[1][t] = __builtin_amdgcn_mfma_f32_16x16x32_bf16(Af[1][s], b, acc[1][t], 0, 0, 0);
            }
        }
    }
#pragma unroll
    for (int r = 0; r < 2; r++) {
#pragma unroll
        for (int reg = 0; reg < 4; reg++) {
            long node = base + r * 16 + quad * 4 + reg;
            if (node < N_NODES) {
                float sw = sumw[node];
#pragma unroll
                for (int t = 0; t < 8; t++) {
                    float v = acc[r][t][reg] + sw * blv[t];
                    v = v > 0.f ? v : 0.2f * v;
                    out[node * 128 + t * 16 + ln15] = v;
                }
            }
        }
    }
}

// ================= launch =================

extern "C" void kernel_launch(void* const* d_in, const int* in_sizes, int n_in,
                              void* d_out, int out_size, void* d_ws, size_t ws_size,
                              hipStream_t stream) {
    const float* x  = (const float*)d_in[0];
    const int* row  = (const int*)d_in[1];
    const int* col  = row + N_EDGES;
    const float* Wq = (const float*)d_in[2];
    const float* Wk = (const float*)d_in[3];
    // d_in[4] = W_v: unused
    const float* Wl = (const float*)d_in[5];
    const float* bl = (const float*)d_in[6];
    float* out = (float*)d_out;

    // workspace carve (~155 MB). MFMA A-loads overread <=96 rows past
    // xaggb/xwb; followed by valid allocations.
    ushort* xb    = (ushort*)d_ws;                        // N*128 bf16 (25.6 MB)
    ushort* qx    = xb + (size_t)N_NODES * DIM;           // N*256 bf16 interleaved q|x (51.2 MB)
    ushort* kactb = qx + (size_t)N_NODES * 256;           // 25.6 MB
    ushort* xaggb = kactb + (size_t)N_NODES * DIM;        // 25.6 MB (xwb aliases: xagg dead after mgemm)
    ushort* xwb   = xaggb;
    ushort* wbuf  = xaggb + (size_t)N_NODES * DIM;        // 4*16384 bf16
    ushort* WqTh = wbuf,             *WqTl = wbuf + 16384;
    ushort* WlTh = wbuf + 2 * 16384, *WlTl = wbuf + 3 * 16384;
    float* sumw = (float*)(wbuf + 4 * 16384);             // N f32
    int* cur  = (int*)(sumw + N_NODES);                   // N (zeroed by prep; ends as degree)
    int* scol = cur + N_NODES;                            // N*CAP (25.6 MB)

    prep_k<<<782, 256, 0, stream>>>(x, Wq, Wk, Wl, xb, qx, kactb,
                                    WqTh, WqTl, WlTh, WlTl, cur);
    scatter_k<<<N_EDGES / 256, 256, 0, stream>>>(row, col, cur, scol);
    xagg_k<<<N_NODES / 16, 256, 0, stream>>>((const uint4*)xb, cur, scol,
                                             (uint4*)xaggb);
    mgemm_k<<<(N_NODES + 127) / 128, 256, 0, stream>>>(xaggb, WqTh, WqTl, qx);
    attn_k<<<N_NODES / 8, 256, 0, stream>>>((const uint2*)kactb, (const uint4*)qx,
                                            cur, scol, (uint2*)xwb, sumw);
    fin_k<<<(N_NODES + 127) / 128, 256, 0, stream>>>(xwb, WlTh, WlTl, bl, sumw, out);
}